// Round 4
// baseline (144.756 us; speedup 1.0000x reference)
//
#include <hip/hip_runtime.h>
#include <math.h>

#define B_N 8192
#define E_N 512
#define T_N 32
#define LDA 40  // A LDS pitch in bf16 elems (32 + 8 pad)
#define LDB 32  // B LDS pitch, UNPADDED: required by global_load_lds lane-contiguity

typedef short bf16x8 __attribute__((ext_vector_type(8)));
typedef float f32x4 __attribute__((ext_vector_type(4)));

// ---------------- ws layout (bytes) ----------------
#define WS_OFFS   256
#define WS_RANK   512
#define WS_ORDER  33280
#define WS_YACC   66048
#define WS_W1T    98816
#define WS_REQ    (WS_W1T + (size_t)T_N * E_N * E_N * 2)

typedef __attribute__((address_space(1))) const unsigned int gas_u32;
typedef __attribute__((address_space(3))) unsigned int las_u32;

static __device__ __forceinline__ unsigned short f2bf(float f) {
    unsigned int u = __float_as_uint(f);
    unsigned int r = u + 0x7fffu + ((u >> 16) & 1u);  // RNE
    return (unsigned short)(r >> 16);
}
static __device__ __forceinline__ unsigned int pack2(float a, float b) {
    return (unsigned int)f2bf(a) | ((unsigned int)f2bf(b) << 16);
}

// ---------- fused pre-pass: W1 transpose-convert (blocks 0..2047) + prep (block 2048) ----------
__global__ __launch_bounds__(256) void k_pre(
    const float* __restrict__ W1, unsigned short* __restrict__ W1T,
    const int* __restrict__ tv, int* __restrict__ offs_g,
    int* __restrict__ rank, int* __restrict__ order, float* __restrict__ yacc) {
    int cid = blockIdx.x, tid = threadIdx.x;
    if (cid < 2048) {
        __shared__ float T[64][65];
        int t = cid >> 6, r = cid & 63;
        int k0 = (r >> 3) * 64, n0 = (r & 7) * 64;
        int g = tid >> 4, c = tid & 15;
#pragma unroll
        for (int p = 0; p < 4; ++p) {
            int row = p * 16 + g;  // k within tile
            float4 v = *(const float4*)(W1 + ((size_t)t * E_N + k0 + row) * E_N + n0 + c * 4);
            T[c * 4 + 0][row] = v.x;
            T[c * 4 + 1][row] = v.y;
            T[c * 4 + 2][row] = v.z;
            T[c * 4 + 3][row] = v.w;
        }
        __syncthreads();
#pragma unroll
        for (int p = 0; p < 4; ++p) {
            int n = p * 16 + g;
            ushort4 o;
            o.x = f2bf(T[n][c * 4 + 0]);
            o.y = f2bf(T[n][c * 4 + 1]);
            o.z = f2bf(T[n][c * 4 + 2]);
            o.w = f2bf(T[n][c * 4 + 3]);
            *(ushort4*)(W1T + ((size_t)t * E_N + n0 + n) * E_N + k0 + c * 4) = o;
        }
    } else {
        // prep: hist + scan + rank/order + yacc zero (256 threads, 32 items each)
        __shared__ int lh[4][32], wcur[4][32], offs_s[33];
        int w = tid >> 6;
        if (tid < 128) lh[tid >> 5][tid & 31] = 0;
        __syncthreads();
        int tval[32];
#pragma unroll
        for (int c = 0; c < 32; ++c) tval[c] = tv[c * 256 + tid];
#pragma unroll
        for (int c = 0; c < 32; ++c) atomicAdd(&lh[w][tval[c]], 1);
        __syncthreads();
        if (tid < 32) {  // wave 0; shfl sources are active lanes <32 only
            int s = lh[0][tid] + lh[1][tid] + lh[2][tid] + lh[3][tid];
            int excl = 0;
#pragma unroll
            for (int i = 0; i < 32; ++i) {
                int v = __shfl(s, i, 64);
                if (i < tid) excl += v;
            }
            offs_s[tid] = excl;
            offs_g[tid] = excl;
            if (tid == 31) { offs_s[32] = excl + s; offs_g[32] = excl + s; }
        }
        __syncthreads();
        if (tid < 128) {
            int ww = tid >> 5, t = tid & 31;
            int s = offs_s[t];
            for (int w2 = 0; w2 < ww; ++w2) s += lh[w2][t];
            wcur[ww][t] = s;
        }
        __syncthreads();
#pragma unroll
        for (int c = 0; c < 32; ++c) {
            int b = c * 256 + tid;
            int pos = atomicAdd(&wcur[w][tval[c]], 1);
            rank[b] = pos;
            order[pos] = b;
        }
        float4 z = make_float4(0.f, 0.f, 0.f, 0.f);
#pragma unroll
        for (int c = 0; c < 8; ++c) *(float4*)(yacc + (c * 256 + tid) * 4) = z;
    }
}

// ---------- MFMA GEMM v3: post-barrier prefetch, async B via global_load_lds ----------
__global__ __launch_bounds__(256) void k_gemm_mfma(
    const float* __restrict__ g_exp, const unsigned short* __restrict__ W1T,
    const float* __restrict__ b1, const float* __restrict__ W2,
    const int* __restrict__ offs, const int* __restrict__ order,
    float* __restrict__ yacc) {
    int wi = blockIdx.x;
    int mt = wi >> 7;  // m-tile slowest: live blocks pack onto distinct CUs
    int rem = wi & 127;
    int t = rem >> 2, nt = rem & 3;
    int base = offs[t];
    int n_t = offs[t + 1] - base;
    int m0 = mt * 128;
    if (m0 >= n_t) return;
    int n0 = nt * 128;

    __shared__ __align__(16) unsigned short As[2][128 * LDA];
    __shared__ __align__(16) unsigned short Bs[2][128 * LDB];

    int tid = threadIdx.x;
    int wave = tid >> 6, lane = tid & 63;
    int quad = lane >> 4, l15 = lane & 15;
    int wm = (wave >> 1) * 64, wn = (wave & 1) * 64;

    // A staging: thread covers rows (tid>>2) and (tid>>2)+64, k-chunk tid&3 (8 floats)
    int s_row0 = tid >> 2, s_c = tid & 3;
    int i0 = base + m0 + s_row0;       if (i0 > B_N - 1) i0 = B_N - 1;
    int i1 = base + m0 + s_row0 + 64;  if (i1 > B_N - 1) i1 = B_N - 1;
    int sidx0 = order[i0], sidx1 = order[i1];
    const float* a0p = g_exp + (size_t)sidx0 * E_N + s_c * 8;
    const float* a1p = g_exp + (size_t)sidx1 * E_N + s_c * 8;
    const unsigned short* Bsrc = W1T + ((size_t)t * E_N + n0) * E_N;

    f32x4 acc[4][4];
#pragma unroll
    for (int mi = 0; mi < 4; ++mi)
#pragma unroll
        for (int ni = 0; ni < 4; ++ni) acc[mi][ni] = (f32x4){0.f, 0.f, 0.f, 0.f};

    // ---- prologue: tile 0 into buffer 0 ----
#pragma unroll
    for (int p = 0; p < 2; ++p) {
        int idx = p * 256 + tid;  // row=idx>>2, kc=idx&3; LDS dest idx*16B (lane-contiguous)
        const unsigned short* gp = Bsrc + (size_t)(idx >> 2) * E_N + (idx & 3) * 8;
        __builtin_amdgcn_global_load_lds((gas_u32*)gp, (las_u32*)&Bs[0][idx * 8], 16, 0, 0);
    }
    {
        float4 q0 = *(const float4*)(a0p), q1 = *(const float4*)(a0p + 4);
        float4 q2 = *(const float4*)(a1p), q3 = *(const float4*)(a1p + 4);
        uint4 w0 = {pack2(q0.x, q0.y), pack2(q0.z, q0.w), pack2(q1.x, q1.y), pack2(q1.z, q1.w)};
        uint4 w1 = {pack2(q2.x, q2.y), pack2(q2.z, q2.w), pack2(q3.x, q3.y), pack2(q3.z, q3.w)};
        *(uint4*)(&As[0][s_row0 * LDA + s_c * 8]) = w0;
        *(uint4*)(&As[0][(s_row0 + 64) * LDA + s_c * 8]) = w1;
    }

    int buf = 0;
    for (int it = 0; it < 16; ++it) {
        __syncthreads();  // tile `it` complete in LDS[buf] (drains lds-DMA + ds_writes)
        bool pre = (it + 1 < 16);
        float4 q0, q1, q2, q3;
        if (pre) {
            int k0n = (it + 1) * 32;
            // async B -> other LDS buffer: in flight across the whole MFMA phase
#pragma unroll
            for (int p = 0; p < 2; ++p) {
                int idx = p * 256 + tid;
                const unsigned short* gp = Bsrc + (size_t)(idx >> 2) * E_N + k0n + (idx & 3) * 8;
                __builtin_amdgcn_global_load_lds((gas_u32*)gp, (las_u32*)&Bs[buf ^ 1][idx * 8], 16, 0, 0);
            }
            q0 = *(const float4*)(a0p + k0n);
            q1 = *(const float4*)(a0p + k0n + 4);
            q2 = *(const float4*)(a1p + k0n);
            q3 = *(const float4*)(a1p + k0n + 4);
        }
        bf16x8 af[4], bfr[4];
#pragma unroll
        for (int i = 0; i < 4; ++i) {
            af[i]  = *(const bf16x8*)(&As[buf][(wm + i * 16 + l15) * LDA + quad * 8]);
            bfr[i] = *(const bf16x8*)(&Bs[buf][(wn + i * 16 + l15) * LDB + quad * 8]);
        }
#pragma unroll
        for (int mi = 0; mi < 4; ++mi)
#pragma unroll
            for (int ni = 0; ni < 4; ++ni)
                acc[mi][ni] = __builtin_amdgcn_mfma_f32_16x16x32_bf16(
                    af[mi], bfr[ni], acc[mi][ni], 0, 0, 0);
        if (pre) {  // A regs (loaded pre-MFMA) -> bf16 -> other buffer
            uint4 w0 = {pack2(q0.x, q0.y), pack2(q0.z, q0.w), pack2(q1.x, q1.y), pack2(q1.z, q1.w)};
            uint4 w1 = {pack2(q2.x, q2.y), pack2(q2.z, q2.w), pack2(q3.x, q3.y), pack2(q3.z, q3.w)};
            *(uint4*)(&As[buf ^ 1][s_row0 * LDA + s_c * 8]) = w0;
            *(uint4*)(&As[buf ^ 1][(s_row0 + 64) * LDA + s_c * 8]) = w1;
        }
        buf ^= 1;
    }

    // epilogue: gelu(acc + b1) * W2, partial dot over this block's 128 cols
    float pr[4][4];
#pragma unroll
    for (int mi = 0; mi < 4; ++mi)
#pragma unroll
        for (int r = 0; r < 4; ++r) pr[mi][r] = 0.f;
#pragma unroll
    for (int ni = 0; ni < 4; ++ni) {
        int n = n0 + wn + ni * 16 + l15;
        float bb = b1[t * E_N + n];
        float w2 = W2[t * E_N + n];
#pragma unroll
        for (int mi = 0; mi < 4; ++mi)
#pragma unroll
            for (int r = 0; r < 4; ++r) {
                float u = acc[mi][ni][r] + bb;
                float gg = 0.5f * u * (1.f + erff(u * 0.70710678118654752f));
                pr[mi][r] = fmaf(gg, w2, pr[mi][r]);
            }
    }
#pragma unroll
    for (int off = 1; off <= 8; off <<= 1)
#pragma unroll
        for (int mi = 0; mi < 4; ++mi)
#pragma unroll
            for (int r = 0; r < 4; ++r) pr[mi][r] += __shfl_xor(pr[mi][r], off, 64);

    if (l15 == 0) {
#pragma unroll
        for (int mi = 0; mi < 4; ++mi)
#pragma unroll
            for (int r = 0; r < 4; ++r) {
                int row = m0 + wm + mi * 16 + quad * 4 + r;
                if (row < n_t) atomicAdd(&yacc[base + row], pr[mi][r]);
            }
    }
}

__global__ void k_final(const float* __restrict__ yacc, const int* __restrict__ rank,
                        const int* __restrict__ tv, const float* __restrict__ b2,
                        float* __restrict__ out, int use_rank) {
    int b = blockIdx.x * blockDim.x + threadIdx.x;
    if (b < B_N) {
        int idx = use_rank ? rank[b] : b;
        float x = yacc[idx] + b2[tv[b]];
        out[b] = fmaxf(x, 0.f) + log1pf(expf(-fabsf(x)));  // stable softplus
    }
}

// ================= fallback (fp32 path, proven) =================
__global__ __launch_bounds__(256) void k_prep_sb(
    const int* __restrict__ tv, int* __restrict__ offs_g,
    int* __restrict__ rank, int* __restrict__ order, float* __restrict__ yacc) {
    __shared__ int lh[4][32], wcur[4][32], offs_s[33];
    int tid = threadIdx.x, w = tid >> 6;
    if (tid < 128) lh[tid >> 5][tid & 31] = 0;
    __syncthreads();
    int tval[32];
#pragma unroll
    for (int c = 0; c < 32; ++c) tval[c] = tv[c * 256 + tid];
#pragma unroll
    for (int c = 0; c < 32; ++c) atomicAdd(&lh[w][tval[c]], 1);
    __syncthreads();
    if (tid < 32) {
        int s = lh[0][tid] + lh[1][tid] + lh[2][tid] + lh[3][tid];
        int excl = 0;
#pragma unroll
        for (int i = 0; i < 32; ++i) {
            int v = __shfl(s, i, 64);
            if (i < tid) excl += v;
        }
        offs_s[tid] = excl;
        offs_g[tid] = excl;
        if (tid == 31) { offs_s[32] = excl + s; offs_g[32] = excl + s; }
    }
    __syncthreads();
    if (tid < 128) {
        int ww = tid >> 5, t = tid & 31;
        int s = offs_s[t];
        for (int w2 = 0; w2 < ww; ++w2) s += lh[w2][t];
        wcur[ww][t] = s;
    }
    __syncthreads();
#pragma unroll
    for (int c = 0; c < 32; ++c) {
        int b = c * 256 + tid;
        int pos = atomicAdd(&wcur[w][tval[c]], 1);
        rank[b] = pos;
        order[pos] = b;
    }
    float4 z = make_float4(0.f, 0.f, 0.f, 0.f);
#pragma unroll
    for (int c = 0; c < 8; ++c) *(float4*)(yacc + (c * 256 + tid) * 4) = z;
}

__global__ __launch_bounds__(256) void fb_gemm(
    const float* __restrict__ g_exp, const float* __restrict__ W1,
    const float* __restrict__ b1, const float* __restrict__ W2,
    const int* __restrict__ offs, const int* __restrict__ order,
    float* __restrict__ yacc) {
    int t = blockIdx.z;
    int base = offs[t];
    int n_t = offs[t + 1] - base;
    int m0 = blockIdx.y * 64;
    if (m0 >= n_t) return;
    int n0 = blockIdx.x * 128;

    __shared__ float As[32][68];
    __shared__ float Bs[32][128];
    __shared__ int sidx[64];

    int tid = threadIdx.x;
    if (tid < 64) {
        int m = m0 + tid;
        sidx[tid] = (m < n_t) ? order[base + m] : -1;
    }
    __syncthreads();

    int ty = tid >> 4, tx = tid & 15;
    float acc[4][8];
#pragma unroll
    for (int r = 0; r < 4; ++r)
#pragma unroll
        for (int c = 0; c < 8; ++c) acc[r][c] = 0.f;

    for (int k0 = 0; k0 < E_N; k0 += 32) {
#pragma unroll
        for (int p = 0; p < 2; ++p) {
            int idx = tid + 256 * p;
            int row = idx >> 3, kc = idx & 7;
            int s = sidx[row];
            float4 v = make_float4(0.f, 0.f, 0.f, 0.f);
            if (s >= 0) v = *(const float4*)(g_exp + (size_t)s * E_N + k0 + kc * 4);
            As[kc * 4 + 0][row] = v.x;
            As[kc * 4 + 1][row] = v.y;
            As[kc * 4 + 2][row] = v.z;
            As[kc * 4 + 3][row] = v.w;
        }
#pragma unroll
        for (int p = 0; p < 4; ++p) {
            int idx = tid + 256 * p;
            int kr = idx >> 5, c4 = idx & 31;
            *(float4*)(&Bs[kr][c4 * 4]) =
                *(const float4*)(W1 + ((size_t)t * E_N + (k0 + kr)) * E_N + n0 + c4 * 4);
        }
        __syncthreads();
#pragma unroll
        for (int e = 0; e < 32; ++e) {
            float4 a = *(const float4*)(&As[e][ty * 4]);
            float4 bA = *(const float4*)(&Bs[e][tx * 4]);
            float4 bB = *(const float4*)(&Bs[e][tx * 4 + 64]);
            float av[4] = {a.x, a.y, a.z, a.w};
            float bv[8] = {bA.x, bA.y, bA.z, bA.w, bB.x, bB.y, bB.z, bB.w};
#pragma unroll
            for (int r = 0; r < 4; ++r)
#pragma unroll
                for (int c = 0; c < 8; ++c) acc[r][c] = fmaf(av[r], bv[c], acc[r][c]);
        }
        __syncthreads();
    }

    float pr[4] = {0.f, 0.f, 0.f, 0.f};
#pragma unroll
    for (int c = 0; c < 8; ++c) {
        int n = n0 + tx * 4 + ((c >= 4) ? 64 : 0) + (c & 3);
        float bb = b1[t * E_N + n];
        float w2 = W2[t * E_N + n];
#pragma unroll
        for (int r = 0; r < 4; ++r) {
            float u = acc[r][c] + bb;
            float g = 0.5f * u * (1.f + erff(u * 0.70710678118654752f));
            pr[r] = fmaf(g, w2, pr[r]);
        }
    }
#pragma unroll
    for (int off = 8; off >= 1; off >>= 1)
#pragma unroll
        for (int r = 0; r < 4; ++r) pr[r] += __shfl_xor(pr[r], off, 64);

    if (tx == 0) {
#pragma unroll
        for (int r = 0; r < 4; ++r) {
            int m = m0 + ty * 4 + r;
            if (m < n_t) atomicAdd(&yacc[sidx[ty * 4 + r]], pr[r]);
        }
    }
}

extern "C" void kernel_launch(void* const* d_in, const int* in_sizes, int n_in,
                              void* d_out, int out_size, void* d_ws, size_t ws_size,
                              hipStream_t stream) {
    const float* g_exp = (const float*)d_in[0];
    const int*   tv    = (const int*)d_in[1];
    const float* W1    = (const float*)d_in[2];
    const float* b1    = (const float*)d_in[3];
    const float* W2    = (const float*)d_in[4];
    const float* b2    = (const float*)d_in[5];
    float* out = (float*)d_out;

    char* ws = (char*)d_ws;
    int* offs   = (int*)(ws + WS_OFFS);
    int* rank   = (int*)(ws + WS_RANK);
    int* order  = (int*)(ws + WS_ORDER);
    float* yacc = (float*)(ws + WS_YACC);

    if (ws_size >= WS_REQ) {
        unsigned short* W1T = (unsigned short*)(ws + WS_W1T);
        k_pre<<<2049, 256, 0, stream>>>(W1, W1T, tv, offs, rank, order, yacc);
        k_gemm_mfma<<<512, 256, 0, stream>>>(g_exp, W1T, b1, W2, offs, order, yacc);
        k_final<<<32, 256, 0, stream>>>(yacc, rank, tv, b2, out, 1);
    } else {
        k_prep_sb<<<1, 256, 0, stream>>>(tv, offs, rank, order, yacc);
        fb_gemm<<<dim3(4, 8, 32), 256, 0, stream>>>(g_exp, W1, b1, W2, offs, order, yacc);
        k_final<<<32, 256, 0, stream>>>(yacc, rank, tv, b2, out, 0);
    }
}

// Round 5
// 133.330 us; speedup vs baseline: 1.0857x; 1.0857x over previous
//
#include <hip/hip_runtime.h>
#include <math.h>

#define B_N 8192
#define E_N 512
#define T_N 32
#define DEPTH 5  // LDS pipeline buffers: 4 tiles in flight, vmcnt never drains to 0 mid-loop

typedef short bf16x8 __attribute__((ext_vector_type(8)));
typedef float f32x4 __attribute__((ext_vector_type(4)));

// ---------------- ws layout (bytes) ----------------
#define WS_OFFS   256
#define WS_RANK   512
#define WS_ORDER  33280
#define WS_YACC   66048
#define WS_ABF    98816                       // bf16 g_exp, unsorted [8192][512]
#define WS_W1T    (WS_ABF + 8388608)          // bf16 W1 transposed [32][512(n)][512(k)]
#define WS_REQ    (WS_W1T + 33554432/2)       // + 16 MB

typedef __attribute__((address_space(1))) const unsigned int gas_u32;
typedef __attribute__((address_space(3))) unsigned int las_u32;

static __device__ __forceinline__ unsigned short f2bf(float f) {
    unsigned int u = __float_as_uint(f);
    unsigned int r = u + 0x7fffu + ((u >> 16) & 1u);  // RNE
    return (unsigned short)(r >> 16);
}

// ---------- fused pre-pass ----------
// blocks [0,2048):    W1[t][k][n] fp32 -> W1T[t][n][k] bf16 (64x64 LDS transpose)
// blocks [2048,2304): g_exp fp32 -> Abf bf16 (elementwise, unsorted; no rank dependency)
// block  2304:        hist + scan + rank/order + yacc zero
__global__ __launch_bounds__(256) void k_pre(
    const float* __restrict__ W1, unsigned short* __restrict__ W1T,
    const float* __restrict__ g_exp, unsigned short* __restrict__ Abf,
    const int* __restrict__ tv, int* __restrict__ offs_g,
    int* __restrict__ rank, int* __restrict__ order, float* __restrict__ yacc) {
    int cid = blockIdx.x, tid = threadIdx.x;
    if (cid < 2048) {
        __shared__ float T[64][65];
        int t = cid >> 6, r = cid & 63;
        int k0 = (r >> 3) * 64, n0 = (r & 7) * 64;
        int g = tid >> 4, c = tid & 15;
#pragma unroll
        for (int p = 0; p < 4; ++p) {
            int row = p * 16 + g;  // k within tile
            float4 v = *(const float4*)(W1 + ((size_t)t * E_N + k0 + row) * E_N + n0 + c * 4);
            T[c * 4 + 0][row] = v.x;
            T[c * 4 + 1][row] = v.y;
            T[c * 4 + 2][row] = v.z;
            T[c * 4 + 3][row] = v.w;
        }
        __syncthreads();
#pragma unroll
        for (int p = 0; p < 4; ++p) {
            int n = p * 16 + g;
            ushort4 o;
            o.x = f2bf(T[n][c * 4 + 0]);
            o.y = f2bf(T[n][c * 4 + 1]);
            o.z = f2bf(T[n][c * 4 + 2]);
            o.w = f2bf(T[n][c * 4 + 3]);
            *(ushort4*)(W1T + ((size_t)t * E_N + n0 + n) * E_N + k0 + c * 4) = o;
        }
    } else if (cid < 2304) {
        int b0 = (cid - 2048) * 32;  // 32 rows per block
#pragma unroll 4
        for (int pp = 0; pp < 16; ++pp) {
            int idx = pp * 256 + tid;
            int row = idx >> 7, c = idx & 127;
            float4 v = *(const float4*)(g_exp + ((size_t)(b0 + row)) * E_N + c * 4);
            ushort4 o;
            o.x = f2bf(v.x); o.y = f2bf(v.y); o.z = f2bf(v.z); o.w = f2bf(v.w);
            *(ushort4*)(Abf + ((size_t)(b0 + row)) * E_N + c * 4) = o;
        }
    } else {
        __shared__ int lh[4][32], wcur[4][32], offs_s[33];
        int w = tid >> 6;
        if (tid < 128) lh[tid >> 5][tid & 31] = 0;
        __syncthreads();
        int tval[32];
#pragma unroll
        for (int c = 0; c < 32; ++c) tval[c] = tv[c * 256 + tid];
#pragma unroll
        for (int c = 0; c < 32; ++c) atomicAdd(&lh[w][tval[c]], 1);
        __syncthreads();
        if (tid < 32) {
            int s = lh[0][tid] + lh[1][tid] + lh[2][tid] + lh[3][tid];
            int excl = 0;
#pragma unroll
            for (int i = 0; i < 32; ++i) {
                int v = __shfl(s, i, 64);
                if (i < tid) excl += v;
            }
            offs_s[tid] = excl;
            offs_g[tid] = excl;
            if (tid == 31) { offs_s[32] = excl + s; offs_g[32] = excl + s; }
        }
        __syncthreads();
        if (tid < 128) {
            int ww = tid >> 5, t = tid & 31;
            int s = offs_s[t];
            for (int w2 = 0; w2 < ww; ++w2) s += lh[w2][t];
            wcur[ww][t] = s;
        }
        __syncthreads();
#pragma unroll
        for (int c = 0; c < 32; ++c) {
            int b = c * 256 + tid;
            int pos = atomicAdd(&wcur[w][tval[c]], 1);
            rank[b] = pos;
            order[pos] = b;
        }
        float4 z = make_float4(0.f, 0.f, 0.f, 0.f);
#pragma unroll
        for (int c = 0; c < 8; ++c) *(float4*)(yacc + (c * 256 + tid) * 4) = z;
    }
}

// ---------- MFMA GEMM v4: DEPTH-buffer DMA pipeline, raw s_barrier + vmcnt(N) ----------
__global__ __launch_bounds__(256) void k_gemm_mfma(
    const unsigned short* __restrict__ Abf, const unsigned short* __restrict__ W1T,
    const float* __restrict__ b1, const float* __restrict__ W2,
    const int* __restrict__ offs, const int* __restrict__ order,
    float* __restrict__ yacc) {
    int wi = blockIdx.x;
    int mt = wi >> 7;  // m-tile slowest: live blocks pack onto distinct CUs
    int rem = wi & 127;
    int t = rem >> 2, nt = rem & 3;
    int base = offs[t];
    int n_t = offs[t + 1] - base;
    int m0 = mt * 128;
    if (m0 >= n_t) return;
    int n0 = nt * 128;

    __shared__ __align__(16) unsigned short As[DEPTH][128 * 32];
    __shared__ __align__(16) unsigned short Bs[DEPTH][128 * 32];

    int tid = threadIdx.x;
    int wave = tid >> 6, lane = tid & 63;
    int quad = lane >> 4, l15 = lane & 15;
    int wm = (wave >> 1) * 64, wn = (wave & 1) * 64;

    // DMA mapping: dest chunk idx (16B units) holds global chunk (row=idx>>2, kc=(idx&3)^(row&3)).
    // XOR swizzle keeps fragment ds_read_b128 uniformly spread over the 8 bank-groups.
    int idx0 = tid, idx1 = tid + 256;
    int r0 = idx0 >> 2;
    int kc = (idx0 & 3) ^ (r0 & 3);  // same for idx1 since (r0+64)&3 == r0&3
    int r1 = r0 + 64;
    int i0 = base + m0 + r0; if (i0 > B_N - 1) i0 = B_N - 1;
    int i1 = base + m0 + r1; if (i1 > B_N - 1) i1 = B_N - 1;
    int o0 = order[i0], o1 = order[i1];
    const unsigned short* pA0 = Abf + (size_t)o0 * E_N + kc * 8;
    const unsigned short* pA1 = Abf + (size_t)o1 * E_N + kc * 8;
    const unsigned short* pB0 = W1T + ((size_t)t * E_N + n0 + r0) * E_N + kc * 8;
    const unsigned short* pB1 = W1T + ((size_t)t * E_N + n0 + r1) * E_N + kc * 8;

    f32x4 acc[4][4];
#pragma unroll
    for (int mi = 0; mi < 4; ++mi)
#pragma unroll
        for (int ni = 0; ni < 4; ++ni) acc[mi][ni] = (f32x4){0.f, 0.f, 0.f, 0.f};

#define ISSUE(kk) do {                                                                              \
        __builtin_amdgcn_global_load_lds((gas_u32*)(pB0 + (kk) * 32),                               \
                                         (las_u32*)&Bs[(kk) % DEPTH][idx0 * 8], 16, 0, 0);          \
        __builtin_amdgcn_global_load_lds((gas_u32*)(pB1 + (kk) * 32),                               \
                                         (las_u32*)&Bs[(kk) % DEPTH][idx1 * 8], 16, 0, 0);          \
        __builtin_amdgcn_global_load_lds((gas_u32*)(pA0 + (kk) * 32),                               \
                                         (las_u32*)&As[(kk) % DEPTH][idx0 * 8], 16, 0, 0);          \
        __builtin_amdgcn_global_load_lds((gas_u32*)(pA1 + (kk) * 32),                               \
                                         (las_u32*)&As[(kk) % DEPTH][idx1 * 8], 16, 0, 0);          \
    } while (0)

    ISSUE(0); ISSUE(1); ISSUE(2); ISSUE(3);

    int aoff[4], boff[4];
#pragma unroll
    for (int i = 0; i < 4; ++i) {
        aoff[i] = ((wm + i * 16 + l15) * 4 + (quad ^ (l15 & 3))) * 8;
        boff[i] = ((wn + i * 16 + l15) * 4 + (quad ^ (l15 & 3))) * 8;
    }

    // Stage it: wait tile it landed (its 4 DMAs are strictly older than the 12 of tiles
    // it+1..it+3, so vmcnt(12) always drains it), barrier (NO vmcnt(0) drain!), compute,
    // then refill buffer (it+4)%DEPTH — last read at stage it-1, sealed by this barrier.
#define STAGE(it, W) do {                                                                           \
        asm volatile("s_waitcnt vmcnt(%0)" :: "n"(W) : "memory");                                   \
        asm volatile("s_barrier" ::: "memory");                                                     \
        const unsigned short* Ab = &As[(it) % DEPTH][0];                                            \
        const unsigned short* Bb = &Bs[(it) % DEPTH][0];                                            \
        bf16x8 af[4], bfr[4];                                                                       \
        _Pragma("unroll") for (int i = 0; i < 4; ++i) {                                             \
            af[i]  = *(const bf16x8*)(Ab + aoff[i]);                                                \
            bfr[i] = *(const bf16x8*)(Bb + boff[i]);                                                \
        }                                                                                           \
        _Pragma("unroll") for (int mi = 0; mi < 4; ++mi)                                            \
            _Pragma("unroll") for (int ni = 0; ni < 4; ++ni)                                        \
                acc[mi][ni] = __builtin_amdgcn_mfma_f32_16x16x32_bf16(af[mi], bfr[ni],              \
                                                                      acc[mi][ni], 0, 0, 0);        \
        if ((it) + 4 < 16) ISSUE((it) + 4);                                                         \
    } while (0)

    STAGE(0, 12);  STAGE(1, 12);  STAGE(2, 12);  STAGE(3, 12);
    STAGE(4, 12);  STAGE(5, 12);  STAGE(6, 12);  STAGE(7, 12);
    STAGE(8, 12);  STAGE(9, 12);  STAGE(10, 12); STAGE(11, 12);
    STAGE(12, 12); STAGE(13, 8);  STAGE(14, 4);  STAGE(15, 0);
#undef STAGE
#undef ISSUE

    // epilogue: gelu(acc + b1) * W2, partial dot over this block's 128 cols
    float pr[4][4];
#pragma unroll
    for (int mi = 0; mi < 4; ++mi)
#pragma unroll
        for (int r = 0; r < 4; ++r) pr[mi][r] = 0.f;
#pragma unroll
    for (int ni = 0; ni < 4; ++ni) {
        int n = n0 + wn + ni * 16 + l15;
        float bb = b1[t * E_N + n];
        float w2 = W2[t * E_N + n];
#pragma unroll
        for (int mi = 0; mi < 4; ++mi)
#pragma unroll
            for (int r = 0; r < 4; ++r) {
                float u = acc[mi][ni][r] + bb;
                float gg = 0.5f * u * (1.f + erff(u * 0.70710678118654752f));
                pr[mi][r] = fmaf(gg, w2, pr[mi][r]);
            }
    }
#pragma unroll
    for (int off = 1; off <= 8; off <<= 1)
#pragma unroll
        for (int mi = 0; mi < 4; ++mi)
#pragma unroll
            for (int r = 0; r < 4; ++r) pr[mi][r] += __shfl_xor(pr[mi][r], off, 64);

    if (l15 == 0) {
#pragma unroll
        for (int mi = 0; mi < 4; ++mi)
#pragma unroll
            for (int r = 0; r < 4; ++r) {
                int row = m0 + wm + mi * 16 + quad * 4 + r;
                if (row < n_t) atomicAdd(&yacc[base + row], pr[mi][r]);
            }
    }
}

__global__ void k_final(const float* __restrict__ yacc, const int* __restrict__ rank,
                        const int* __restrict__ tv, const float* __restrict__ b2,
                        float* __restrict__ out, int use_rank) {
    int b = blockIdx.x * blockDim.x + threadIdx.x;
    if (b < B_N) {
        int idx = use_rank ? rank[b] : b;
        float x = yacc[idx] + b2[tv[b]];
        out[b] = fmaxf(x, 0.f) + log1pf(expf(-fabsf(x)));  // stable softplus
    }
}

// ================= fallback (fp32 path, proven) =================
__global__ __launch_bounds__(256) void k_prep_sb(
    const int* __restrict__ tv, int* __restrict__ offs_g,
    int* __restrict__ rank, int* __restrict__ order, float* __restrict__ yacc) {
    __shared__ int lh[4][32], wcur[4][32], offs_s[33];
    int tid = threadIdx.x, w = tid >> 6;
    if (tid < 128) lh[tid >> 5][tid & 31] = 0;
    __syncthreads();
    int tval[32];
#pragma unroll
    for (int c = 0; c < 32; ++c) tval[c] = tv[c * 256 + tid];
#pragma unroll
    for (int c = 0; c < 32; ++c) atomicAdd(&lh[w][tval[c]], 1);
    __syncthreads();
    if (tid < 32) {
        int s = lh[0][tid] + lh[1][tid] + lh[2][tid] + lh[3][tid];
        int excl = 0;
#pragma unroll
        for (int i = 0; i < 32; ++i) {
            int v = __shfl(s, i, 64);
            if (i < tid) excl += v;
        }
        offs_s[tid] = excl;
        offs_g[tid] = excl;
        if (tid == 31) { offs_s[32] = excl + s; offs_g[32] = excl + s; }
    }
    __syncthreads();
    if (tid < 128) {
        int ww = tid >> 5, t = tid & 31;
        int s = offs_s[t];
        for (int w2 = 0; w2 < ww; ++w2) s += lh[w2][t];
        wcur[ww][t] = s;
    }
    __syncthreads();
#pragma unroll
    for (int c = 0; c < 32; ++c) {
        int b = c * 256 + tid;
        int pos = atomicAdd(&wcur[w][tval[c]], 1);
        rank[b] = pos;
        order[pos] = b;
    }
    float4 z = make_float4(0.f, 0.f, 0.f, 0.f);
#pragma unroll
    for (int c = 0; c < 8; ++c) *(float4*)(yacc + (c * 256 + tid) * 4) = z;
}

__global__ __launch_bounds__(256) void fb_gemm(
    const float* __restrict__ g_exp, const float* __restrict__ W1,
    const float* __restrict__ b1, const float* __restrict__ W2,
    const int* __restrict__ offs, const int* __restrict__ order,
    float* __restrict__ yacc) {
    int t = blockIdx.z;
    int base = offs[t];
    int n_t = offs[t + 1] - base;
    int m0 = blockIdx.y * 64;
    if (m0 >= n_t) return;
    int n0 = blockIdx.x * 128;

    __shared__ float As[32][68];
    __shared__ float Bs[32][128];
    __shared__ int sidx[64];

    int tid = threadIdx.x;
    if (tid < 64) {
        int m = m0 + tid;
        sidx[tid] = (m < n_t) ? order[base + m] : -1;
    }
    __syncthreads();

    int ty = tid >> 4, tx = tid & 15;
    float acc[4][8];
#pragma unroll
    for (int r = 0; r < 4; ++r)
#pragma unroll
        for (int c = 0; c < 8; ++c) acc[r][c] = 0.f;

    for (int k0 = 0; k0 < E_N; k0 += 32) {
#pragma unroll
        for (int p = 0; p < 2; ++p) {
            int idx = tid + 256 * p;
            int row = idx >> 3, kcq = idx & 7;
            int s = sidx[row];
            float4 v = make_float4(0.f, 0.f, 0.f, 0.f);
            if (s >= 0) v = *(const float4*)(g_exp + (size_t)s * E_N + k0 + kcq * 4);
            As[kcq * 4 + 0][row] = v.x;
            As[kcq * 4 + 1][row] = v.y;
            As[kcq * 4 + 2][row] = v.z;
            As[kcq * 4 + 3][row] = v.w;
        }
#pragma unroll
        for (int p = 0; p < 4; ++p) {
            int idx = tid + 256 * p;
            int kr = idx >> 5, c4 = idx & 31;
            *(float4*)(&Bs[kr][c4 * 4]) =
                *(const float4*)(W1 + ((size_t)t * E_N + (k0 + kr)) * E_N + n0 + c4 * 4);
        }
        __syncthreads();
#pragma unroll
        for (int e = 0; e < 32; ++e) {
            float4 a = *(const float4*)(&As[e][ty * 4]);
            float4 bA = *(const float4*)(&Bs[e][tx * 4]);
            float4 bB = *(const float4*)(&Bs[e][tx * 4 + 64]);
            float av[4] = {a.x, a.y, a.z, a.w};
            float bv[8] = {bA.x, bA.y, bA.z, bA.w, bB.x, bB.y, bB.z, bB.w};
#pragma unroll
            for (int r = 0; r < 4; ++r)
#pragma unroll
                for (int c = 0; c < 8; ++c) acc[r][c] = fmaf(av[r], bv[c], acc[r][c]);
        }
        __syncthreads();
    }

    float pr[4] = {0.f, 0.f, 0.f, 0.f};
#pragma unroll
    for (int c = 0; c < 8; ++c) {
        int n = n0 + tx * 4 + ((c >= 4) ? 64 : 0) + (c & 3);
        float bb = b1[t * E_N + n];
        float w2 = W2[t * E_N + n];
#pragma unroll
        for (int r = 0; r < 4; ++r) {
            float u = acc[r][c] + bb;
            float g = 0.5f * u * (1.f + erff(u * 0.70710678118654752f));
            pr[r] = fmaf(g, w2, pr[r]);
        }
    }
#pragma unroll
    for (int off = 8; off >= 1; off >>= 1)
#pragma unroll
        for (int r = 0; r < 4; ++r) pr[r] += __shfl_xor(pr[r], off, 64);

    if (tx == 0) {
#pragma unroll
        for (int r = 0; r < 4; ++r) {
            int m = m0 + ty * 4 + r;
            if (m < n_t) atomicAdd(&yacc[sidx[ty * 4 + r]], pr[r]);
        }
    }
}

extern "C" void kernel_launch(void* const* d_in, const int* in_sizes, int n_in,
                              void* d_out, int out_size, void* d_ws, size_t ws_size,
                              hipStream_t stream) {
    const float* g_exp = (const float*)d_in[0];
    const int*   tv    = (const int*)d_in[1];
    const float* W1    = (const float*)d_in[2];
    const float* b1    = (const float*)d_in[3];
    const float* W2    = (const float*)d_in[4];
    const float* b2    = (const float*)d_in[5];
    float* out = (float*)d_out;

    char* ws = (char*)d_ws;
    int* offs   = (int*)(ws + WS_OFFS);
    int* rank   = (int*)(ws + WS_RANK);
    int* order  = (int*)(ws + WS_ORDER);
    float* yacc = (float*)(ws + WS_YACC);

    if (ws_size >= (size_t)WS_REQ) {
        unsigned short* Abf = (unsigned short*)(ws + WS_ABF);
        unsigned short* W1T = (unsigned short*)(ws + WS_W1T);
        k_pre<<<2305, 256, 0, stream>>>(W1, W1T, g_exp, Abf, tv, offs, rank, order, yacc);
        k_gemm_mfma<<<512, 256, 0, stream>>>(Abf, W1T, b1, W2, offs, order, yacc);
        k_final<<<32, 256, 0, stream>>>(yacc, rank, tv, b2, out, 1);
    } else {
        k_prep_sb<<<1, 256, 0, stream>>>(tv, offs, rank, order, yacc);
        fb_gemm<<<dim3(4, 8, 32), 256, 0, stream>>>(g_exp, W1, b1, W2, offs, order, yacc);
        k_final<<<32, 256, 0, stream>>>(yacc, rank, tv, b2, out, 0);
    }
}